// Round 14
// baseline (1772.002 us; speedup 1.0000x reference)
//
#include <hip/hip_runtime.h>

#define BATCH 256
#define TSTEPS 4096
#define HID 136
#define HPADH 144     // h padded to 144 f16 (288 B); f16 slots 136..143 stay 0
#define ODIM 68
#define THREADS 512   // 8 waves: waves 0-3 -> batch 2B, waves 4-7 -> batch 2B+1
#define NBLK (BATCH / 2)

typedef _Float16 h2 __attribute__((ext_vector_type(2)));

__device__ __forceinline__ float fast_tanh(float z) {
    float az = fabsf(z);
    float e = __expf(-2.0f * az);
    float r = (1.0f - e) * __builtin_amdgcn_rcpf(1.0f + e);
    return copysignf(r, z);
}

template <int CTRL>
__device__ __forceinline__ float dpp_add(float x) {
    int y = __builtin_amdgcn_update_dpp(0, __float_as_int(x), CTRL, 0xF, 0xF, false);
    return x + __int_as_float(y);
}
// butterfly over 8 consecutive lanes: all 8 end with the full sum
__device__ __forceinline__ float reduce8(float x) {
    x = dpp_add<0xB1>(x);    // quad_perm xor1
    x = dpp_add<0x4E>(x);    // quad_perm xor2
    x = dpp_add<0x141>(x);   // row_half_mirror
    return x;
}

__device__ __forceinline__ h2 bc_h2(unsigned int u) {
    union { unsigned int u; h2 h; } c; c.u = u; return c.h;
}

// One step: 3 DS reads (2xb128 + b32), 45 fdot2 (5 rows x 9 pairs),
// 5 reduce8, select, 1 tanh, 1 predicated b16 write. XV is a register float2.
#define RNN_STEP(HR, HW, XV)                                                   \
    {                                                                          \
        uint4 u0 = *(const uint4*)((HR) + 16 * ks);                            \
        uint4 u1 = *(const uint4*)((HR) + 16 * ks + 8);                        \
        unsigned int ut = *(const unsigned int*)((HR) + 128 + 2 * ks);         \
        h2 hq[9];                                                              \
        hq[0] = bc_h2(u0.x); hq[1] = bc_h2(u0.y);                              \
        hq[2] = bc_h2(u0.z); hq[3] = bc_h2(u0.w);                              \
        hq[4] = bc_h2(u1.x); hq[5] = bc_h2(u1.y);                              \
        hq[6] = bc_h2(u1.z); hq[7] = bc_h2(u1.w);                              \
        hq[8] = bc_h2(ut);                                                     \
        float a0 = 0.f, a1 = 0.f, a2 = 0.f, a3 = 0.f, a4 = 0.f;                \
        _Pragma("unroll")                                                      \
        for (int q = 0; q < 9; ++q) {                                          \
            a0 = __builtin_amdgcn_fdot2(hq[q], wq[0][q], a0, false);           \
            a1 = __builtin_amdgcn_fdot2(hq[q], wq[1][q], a1, false);           \
            a2 = __builtin_amdgcn_fdot2(hq[q], wq[2][q], a2, false);           \
            a3 = __builtin_amdgcn_fdot2(hq[q], wq[3][q], a3, false);           \
            a4 = __builtin_amdgcn_fdot2(hq[q], wq[4][q], a4, false);           \
        }                                                                      \
        a0 = reduce8(a0);                                                      \
        a1 = reduce8(a1);                                                      \
        a2 = reduce8(a2);                                                      \
        a3 = reduce8(a3);                                                      \
        a4 = reduce8(a4);                                                      \
        float s = a0;                                                          \
        s = (ks == 1) ? a1 : s;                                                \
        s = (ks == 2) ? a2 : s;                                                \
        s = (ks == 3) ? a3 : s;                                                \
        s = (ks == 4) ? a4 : s;                                                \
        float z = fmaf((XV).x, wih0, fmaf((XV).y, wih1, bias)) + s;            \
        float th = fast_tanh(z);                                               \
        if (ks < 4 || (ks == 4 && grp < 2)) (HW)[zrow] = (_Float16)th;         \
    }

__global__ __launch_bounds__(THREADS)
void rnn_fused_kernel(const float* __restrict__ x,
                      const float* __restrict__ W_ih,
                      const float* __restrict__ W_hh,
                      const float* __restrict__ b_ih,
                      const float* __restrict__ b_hh,
                      const float* __restrict__ W_fc,
                      const float* __restrict__ b_fc,
                      float* __restrict__ out)
{
    __shared__ __align__(16) _Float16 hA[2][HPADH];
    __shared__ __align__(16) _Float16 hB[2][HPADH];

    const int tid = threadIdx.x;
    const int sub = tid >> 8;       // batch substream 0/1 (waves 0-3 vs 4-7)
    const int st  = tid & 255;      // thread index within substream
    const int wvs = st >> 6;        // wave within substream 0..3
    const int grp = (st >> 3) & 7;  // group index within wave 0..7
    const int g   = st >> 3;        // substream group 0..31 (rows 4g..4g+3)
    const int ks  = tid & 7;        // k-lane within group
    const int bb  = blockIdx.x * 2 + sub;   // this substream's batch

    // extra row: 128 + 2*wvs + (g&1)  (128..135; 4 groups redundant each)
    const int erow = 128 + 2 * wvs + (g & 1);

    // ---- persistent W_hh f16 pairs: 5 rows x 9 h2 = 45 VGPR ----
    // k map: q<8 -> k = 16*ks + 2q ; q==8 -> k = 128 + 2*ks
    h2 wq[5][9];
#pragma unroll
    for (int j = 0; j < 5; ++j) {
        const int row = (j < 4) ? (4 * g + j) : erow;
#pragma unroll
        for (int q = 0; q < 9; ++q) {
            const int k = (q < 8) ? (16 * ks + 2 * q) : (128 + 2 * ks);
            const float v0 = (k     < HID) ? W_hh[row * HID + k]     : 0.0f;
            const float v1 = (k + 1 < HID) ? W_hh[row * HID + k + 1] : 0.0f;
            wq[j][q] = h2{(_Float16)v0, (_Float16)v1};
        }
    }
    // lane's finished row: ks 0..3 -> main, ks==4 -> extra, 5..7 dummy
    const int zrow = (ks < 4) ? (4 * g + ks) : (ks == 4) ? erow : (4 * g);
    const float wih0 = W_ih[zrow * 2 + 0];
    const float wih1 = W_ih[zrow * 2 + 1];
    const float bias = b_ih[zrow] + b_hh[zrow];

    // ---- zero h buffers (padding stays zero) ----
    if (st < HPADH) { hA[sub][st] = (_Float16)0.f; hB[sub][st] = (_Float16)0.f; }
    __syncthreads();

    _Float16* const hAs = hA[sub];
    _Float16* const hBs = hB[sub];

    // ---- x streamed from global, 4 steps (2 iterations) of prefetch ----
    const float2* xg = (const float2*)(x + (size_t)bb * (TSTEPS * 2));
    float2 xc0 = xg[0], xc1 = xg[1];
    float2 xn0 = xg[2], xn1 = xg[3];

    for (int t = 0; t < TSTEPS; t += 2) {
        const int tf = (t + 4) & (TSTEPS - 1);
        const float2 xf0 = xg[tf];
        const float2 xf1 = xg[tf + 1];

        RNN_STEP(hAs, hBs, xc0);
        __syncthreads();
        RNN_STEP(hBs, hAs, xc1);
        __syncthreads();

        xc0 = xn0; xc1 = xn1;
        xn0 = xf0; xn1 = xf1;
    }
    // TSTEPS even -> final h in hA

    // ---- final head: out[bb][o] = h . W_fc[o,:] + b_fc[o] ----
    if (st < ODIM) {
        const int o = st;
        float s = b_fc[o];
#pragma unroll 8
        for (int k = 0; k < HID; ++k)
            s = fmaf((float)hAs[k], W_fc[o * HID + k], s);
        out[bb * ODIM + o] = s;
    }
}

extern "C" void kernel_launch(void* const* d_in, const int* in_sizes, int n_in,
                              void* d_out, int out_size, void* d_ws, size_t ws_size,
                              hipStream_t stream) {
    const float* x    = (const float*)d_in[0];
    const float* W_ih = (const float*)d_in[1];
    const float* W_hh = (const float*)d_in[2];
    const float* b_ih = (const float*)d_in[3];
    const float* b_hh = (const float*)d_in[4];
    const float* W_fc = (const float*)d_in[5];
    const float* b_fc = (const float*)d_in[6];
    float* out = (float*)d_out;

    rnn_fused_kernel<<<NBLK, THREADS, 0, stream>>>(x, W_ih, W_hh, b_ih, b_hh,
                                                   W_fc, b_fc, out);
}

// Round 15
// 1422.523 us; speedup vs baseline: 1.2457x; 1.2457x over previous
//
#include <hip/hip_runtime.h>

#define BATCH 256
#define TSTEPS 4096
#define HID 136
#define ODIM 68
#define THREADS 192   // 3 waves, 1 per SIMD; lane == row, no reduction at all

typedef _Float16 h2 __attribute__((ext_vector_type(2)));

__device__ __forceinline__ float fast_tanh(float z) {
    float az = fabsf(z);
    float e = __expf(-2.0f * az);
    float r = (1.0f - e) * __builtin_amdgcn_rcpf(1.0f + e);
    return copysignf(r, z);
}

__device__ __forceinline__ h2 bc_h2(unsigned int u) {
    union { unsigned int u; h2 h; } c; c.u = u; return c.h;
}

// One step: 17 broadcast ds_read_b128 (whole h, uniform addr per wave),
// 68 fdot2 into 4 independent accumulators, x-proj, tanh, 1 predicated
// b16 write of this lane's row. XV is a register float2.
#define RNN_STEP(HR, HW, XV)                                                   \
    {                                                                          \
        uint4 hc[17];                                                          \
        _Pragma("unroll")                                                      \
        for (int i = 0; i < 17; ++i) hc[i] = ((const uint4*)(HR))[i];          \
        float a0 = 0.f, a1 = 0.f, a2 = 0.f, a3 = 0.f;                          \
        _Pragma("unroll")                                                      \
        for (int i = 0; i < 17; ++i) {                                         \
            a0 = __builtin_amdgcn_fdot2(bc_h2(hc[i].x), w[4 * i + 0], a0, false); \
            a1 = __builtin_amdgcn_fdot2(bc_h2(hc[i].y), w[4 * i + 1], a1, false); \
            a2 = __builtin_amdgcn_fdot2(bc_h2(hc[i].z), w[4 * i + 2], a2, false); \
            a3 = __builtin_amdgcn_fdot2(bc_h2(hc[i].w), w[4 * i + 3], a3, false); \
        }                                                                      \
        float z = (a0 + a1) + (a2 + a3)                                        \
                + fmaf((XV).x, wih0, fmaf((XV).y, wih1, bias));                \
        float th = fast_tanh(z);                                               \
        if (valid) (HW)[row] = (_Float16)th;                                   \
    }

__global__ __launch_bounds__(THREADS)
void rnn_fused_kernel(const float* __restrict__ x,
                      const float* __restrict__ W_ih,
                      const float* __restrict__ W_hh,
                      const float* __restrict__ b_ih,
                      const float* __restrict__ b_hh,
                      const float* __restrict__ W_fc,
                      const float* __restrict__ b_fc,
                      float* __restrict__ out)
{
    __shared__ __align__(16) _Float16 hA[HID];   // 272 B = exactly 17 x b128
    __shared__ __align__(16) _Float16 hB[HID];

    const int b     = blockIdx.x;
    const int tid   = threadIdx.x;
    const int row   = tid;                 // one full row per lane
    const bool valid = (row < HID);
    const int rowc  = valid ? row : 0;     // clamped for weight loads

    // ---- persistent W_hh row in f16 pairs: 68 VGPR ----
    h2 w[68];
#pragma unroll
    for (int p = 0; p < 68; ++p) {
        const float v0 = valid ? W_hh[rowc * HID + 2 * p]     : 0.0f;
        const float v1 = valid ? W_hh[rowc * HID + 2 * p + 1] : 0.0f;
        w[p] = h2{(_Float16)v0, (_Float16)v1};
    }
    const float wih0 = valid ? W_ih[rowc * 2 + 0] : 0.0f;
    const float wih1 = valid ? W_ih[rowc * 2 + 1] : 0.0f;
    const float bias = valid ? (b_ih[rowc] + b_hh[rowc]) : 0.0f;

    // ---- zero h buffers ----
    if (tid < HID / 2) {
        ((unsigned int*)hA)[tid] = 0u;
        ((unsigned int*)hB)[tid] = 0u;
    }
    __syncthreads();

    // ---- x streamed from global, 4 steps (2 iterations) of prefetch ----
    const float2* xg = (const float2*)(x + (size_t)b * (TSTEPS * 2));
    float2 xc0 = xg[0], xc1 = xg[1];
    float2 xn0 = xg[2], xn1 = xg[3];

    for (int t = 0; t < TSTEPS; t += 2) {
        const int tf = (t + 4) & (TSTEPS - 1);
        const float2 xf0 = xg[tf];
        const float2 xf1 = xg[tf + 1];

        RNN_STEP(hA, hB, xc0);
        __syncthreads();
        RNN_STEP(hB, hA, xc1);
        __syncthreads();

        xc0 = xn0; xc1 = xn1;
        xn0 = xf0; xn1 = xf1;
    }
    // TSTEPS even -> final h in hA

    // ---- final head: out[b][o] = h . W_fc[o,:] + b_fc[o] ----
    if (tid < ODIM) {
        const int o = tid;
        float s = b_fc[o];
#pragma unroll 8
        for (int k = 0; k < HID; ++k)
            s = fmaf((float)hA[k], W_fc[o * HID + k], s);
        out[b * ODIM + o] = s;
    }
}

extern "C" void kernel_launch(void* const* d_in, const int* in_sizes, int n_in,
                              void* d_out, int out_size, void* d_ws, size_t ws_size,
                              hipStream_t stream) {
    const float* x    = (const float*)d_in[0];
    const float* W_ih = (const float*)d_in[1];
    const float* W_hh = (const float*)d_in[2];
    const float* b_ih = (const float*)d_in[3];
    const float* b_hh = (const float*)d_in[4];
    const float* W_fc = (const float*)d_in[5];
    const float* b_fc = (const float*)d_in[6];
    float* out = (float*)d_out;

    rnn_fused_kernel<<<BATCH, THREADS, 0, stream>>>(x, W_ih, W_hh, b_ih, b_hh,
                                                    W_fc, b_fc, out);
}

// Round 17
// 1142.222 us; speedup vs baseline: 1.5514x; 1.2454x over previous
//
#include <hip/hip_runtime.h>

#define BATCH 256
#define TSTEPS 4096
#define HID 136
#define HPADH 144     // h padded to 144 f16 (288 B); f16 slots 136..143 stay 0
#define ODIM 68
#define THREADS 256   // 4 waves, exactly 1 per SIMD

typedef _Float16 h2 __attribute__((ext_vector_type(2)));

// 5-instr tanh: 1 - 2/(1+e^{2z}) ; e^{2z} = 2^(z * 2/ln2)
__device__ __forceinline__ float fast_tanh(float z) {
    float e = __builtin_amdgcn_exp2f(z * 2.885390081777927f);
    float r = __builtin_amdgcn_rcpf(1.0f + e);
    return fmaf(-2.0f, r, 1.0f);
}

template <int CTRL>
__device__ __forceinline__ float dpp_add(float x) {
    int y = __builtin_amdgcn_update_dpp(0, __float_as_int(x), CTRL, 0xF, 0xF, false);
    return x + __int_as_float(y);
}

__device__ __forceinline__ h2 bc_h2(unsigned int u) {
    union { unsigned int u; h2 h; } c; c.u = u; return c.h;
}

// One step: 3 DS reads (2xb128 + b32), 45 fdot2 (5 rows x 9 pairs),
// stage-major 8-lane butterfly (no DPP hazard chains), select, 5-instr
// tanh, 1 predicated b16 write. XV is a register float2.
#define RNN_STEP(HR, HW, XV)                                                   \
    {                                                                          \
        uint4 u0 = *(const uint4*)((HR) + 16 * ks);                            \
        uint4 u1 = *(const uint4*)((HR) + 16 * ks + 8);                        \
        unsigned int ut = *(const unsigned int*)((HR) + 128 + 2 * ks);         \
        h2 hq[9];                                                              \
        hq[0] = bc_h2(u0.x); hq[1] = bc_h2(u0.y);                              \
        hq[2] = bc_h2(u0.z); hq[3] = bc_h2(u0.w);                              \
        hq[4] = bc_h2(u1.x); hq[5] = bc_h2(u1.y);                              \
        hq[6] = bc_h2(u1.z); hq[7] = bc_h2(u1.w);                              \
        hq[8] = bc_h2(ut);                                                     \
        float a0 = 0.f, a1 = 0.f, a2 = 0.f, a3 = 0.f, a4 = 0.f;                \
        _Pragma("unroll")                                                      \
        for (int q = 0; q < 9; ++q) {                                          \
            a0 = __builtin_amdgcn_fdot2(hq[q], wq[0][q], a0, false);           \
            a1 = __builtin_amdgcn_fdot2(hq[q], wq[1][q], a1, false);           \
            a2 = __builtin_amdgcn_fdot2(hq[q], wq[2][q], a2, false);           \
            a3 = __builtin_amdgcn_fdot2(hq[q], wq[3][q], a3, false);           \
            a4 = __builtin_amdgcn_fdot2(hq[q], wq[4][q], a4, false);           \
        }                                                                      \
        /* stage-major butterfly: 4 independent ops between dependent pairs */ \
        a0 = dpp_add<0xB1>(a0);  a1 = dpp_add<0xB1>(a1);                       \
        a2 = dpp_add<0xB1>(a2);  a3 = dpp_add<0xB1>(a3);                       \
        a4 = dpp_add<0xB1>(a4);                                                \
        a0 = dpp_add<0x4E>(a0);  a1 = dpp_add<0x4E>(a1);                       \
        a2 = dpp_add<0x4E>(a2);  a3 = dpp_add<0x4E>(a3);                       \
        a4 = dpp_add<0x4E>(a4);                                                \
        a0 = dpp_add<0x141>(a0); a1 = dpp_add<0x141>(a1);                      \
        a2 = dpp_add<0x141>(a2); a3 = dpp_add<0x141>(a3);                      \
        a4 = dpp_add<0x141>(a4);                                               \
        float s = a0;                                                          \
        s = (ks == 1) ? a1 : s;                                                \
        s = (ks == 2) ? a2 : s;                                                \
        s = (ks == 3) ? a3 : s;                                                \
        s = (ks == 4) ? a4 : s;                                                \
        float z = fmaf((XV).x, wih0, fmaf((XV).y, wih1, bias)) + s;            \
        float th = fast_tanh(z);                                               \
        if (wr) (HW)[zrow] = (_Float16)th;                                     \
    }

__global__ __launch_bounds__(THREADS)
void rnn_fused_kernel(const float* __restrict__ x,
                      const float* __restrict__ W_ih,
                      const float* __restrict__ W_hh,
                      const float* __restrict__ b_ih,
                      const float* __restrict__ b_hh,
                      const float* __restrict__ W_fc,
                      const float* __restrict__ b_fc,
                      float* __restrict__ out)
{
    __shared__ __align__(16) _Float16 hA[HPADH];
    __shared__ __align__(16) _Float16 hB[HPADH];

    const int b   = blockIdx.x;
    const int tid = threadIdx.x;
    const int wv  = tid >> 6;       // wave 0..3
    const int g   = tid >> 3;       // global group 0..31 (main rows 4g..4g+3)
    const int ks  = tid & 7;        // k-lane within group

    // extra row: 128 + 2*wv + (g&1)   (128..135; 4 groups redundant each)
    const int erow = 128 + 2 * wv + (g & 1);

    // ---- persistent W_hh f16 pairs: 5 rows x 9 h2 = 45 VGPR ----
    // k map: q<8 -> k = 16*ks + 2q ; q==8 -> k = 128 + 2*ks
    h2 wq[5][9];
#pragma unroll
    for (int j = 0; j < 5; ++j) {
        const int row = (j < 4) ? (4 * g + j) : erow;
#pragma unroll
        for (int q = 0; q < 9; ++q) {
            const int k = (q < 8) ? (16 * ks + 2 * q) : (128 + 2 * ks);
            const float v0 = (k     < HID) ? W_hh[row * HID + k]     : 0.0f;
            const float v1 = (k + 1 < HID) ? W_hh[row * HID + k + 1] : 0.0f;
            wq[j][q] = h2{(_Float16)v0, (_Float16)v1};
        }
    }
    // lane's finished row: ks 0..3 -> main, ks==4 -> extra, 5..7 dummy
    const int zrow = (ks < 4) ? (4 * g + ks) : (ks == 4) ? erow : (4 * g);
    const bool wr  = (ks < 4) || (ks == 4 && ((tid >> 3) & 7) < 2);
    const float wih0 = W_ih[zrow * 2 + 0];
    const float wih1 = W_ih[zrow * 2 + 1];
    const float bias = b_ih[zrow] + b_hh[zrow];

    // ---- zero h buffers (padding stays zero) ----
    if (tid < HPADH) { hA[tid] = (_Float16)0.f; hB[tid] = (_Float16)0.f; }
    __syncthreads();

    // ---- x streamed from global; iteration = 4 steps; depth-2 prefetch ----
    const float4* xg4 = (const float4*)(x + (size_t)b * (TSTEPS * 2));
    float4 xq0 = xg4[0];           // x for steps 0..1
    float4 xq1 = xg4[1];           // x for steps 2..3
    float4 xp0 = xg4[2];           // steps 4..5
    float4 xp1 = xg4[3];           // steps 6..7

    for (int t = 0; t < TSTEPS; t += 4) {
        const int tf = ((t + 8) & (TSTEPS - 1)) >> 1;   // float4 index
        const float4 xf0 = xg4[tf];
        const float4 xf1 = xg4[tf + 1];

        RNN_STEP(hA, hB, make_float2(xq0.x, xq0.y));
        __syncthreads();
        RNN_STEP(hB, hA, make_float2(xq0.z, xq0.w));
        __syncthreads();
        RNN_STEP(hA, hB, make_float2(xq1.x, xq1.y));
        __syncthreads();
        RNN_STEP(hB, hA, make_float2(xq1.z, xq1.w));
        __syncthreads();

        xq0 = xp0; xq1 = xp1;
        xp0 = xf0; xp1 = xf1;
    }
    // TSTEPS % 4 == 0 -> final h in hA

    // ---- final head: out[b][o] = h . W_fc[o,:] + b_fc[o] ----
    if (tid < ODIM) {
        const int o = tid;
        float s = b_fc[o];
#pragma unroll 8
        for (int k = 0; k < HID; ++k)
            s = fmaf((float)hA[k], W_fc[o * HID + k], s);
        out[b * ODIM + o] = s;
    }
}

extern "C" void kernel_launch(void* const* d_in, const int* in_sizes, int n_in,
                              void* d_out, int out_size, void* d_ws, size_t ws_size,
                              hipStream_t stream) {
    const float* x    = (const float*)d_in[0];
    const float* W_ih = (const float*)d_in[1];
    const float* W_hh = (const float*)d_in[2];
    const float* b_ih = (const float*)d_in[3];
    const float* b_hh = (const float*)d_in[4];
    const float* W_fc = (const float*)d_in[5];
    const float* b_fc = (const float*)d_in[6];
    float* out = (float*)d_out;

    rnn_fused_kernel<<<BATCH, THREADS, 0, stream>>>(x, W_ih, W_hh, b_ih, b_hh,
                                                    W_fc, b_fc, out);
}

// Round 18
// 1132.596 us; speedup vs baseline: 1.5645x; 1.0085x over previous
//
#include <hip/hip_runtime.h>

#define BATCH 256
#define TSTEPS 4096
#define HID 136
#define HPADH 144     // h padded to 144 f16 (288 B); f16 slots 136..143 stay 0
#define ODIM 68
#define THREADS 256   // 4 waves, exactly 1 per SIMD

typedef _Float16 h2 __attribute__((ext_vector_type(2)));

// 5-instr tanh: 1 - 2/(1+e^{2z}) ; e^{2z} = 2^(z * 2/ln2)
__device__ __forceinline__ float fast_tanh(float z) {
    float e = __builtin_amdgcn_exp2f(z * 2.885390081777927f);
    float r = __builtin_amdgcn_rcpf(1.0f + e);
    return fmaf(-2.0f, r, 1.0f);
}

template <int CTRL>
__device__ __forceinline__ float dpp_add(float x) {
    int y = __builtin_amdgcn_update_dpp(0, __float_as_int(x), CTRL, 0xF, 0xF, false);
    return x + __int_as_float(y);
}

__device__ __forceinline__ h2 bc_h2(unsigned int u) {
    union { unsigned int u; h2 h; } c; c.u = u; return c.h;
}

// One step: 3 DS reads (2xb128 + b32), 45 fdot2 (5 rows x 9 pairs),
// stage-major 8-lane butterfly, tree select, 5-instr tanh, 1 predicated
// b16 write. XX/XY are register floats (this step's x).
#define RNN_STEP(HR, HW, XX, XY)                                               \
    {                                                                          \
        uint4 u0 = *(const uint4*)((HR) + 16 * ks);                            \
        uint4 u1 = *(const uint4*)((HR) + 16 * ks + 8);                        \
        unsigned int ut = *(const unsigned int*)((HR) + 128 + 2 * ks);         \
        h2 hq[9];                                                              \
        hq[0] = bc_h2(u0.x); hq[1] = bc_h2(u0.y);                              \
        hq[2] = bc_h2(u0.z); hq[3] = bc_h2(u0.w);                              \
        hq[4] = bc_h2(u1.x); hq[5] = bc_h2(u1.y);                              \
        hq[6] = bc_h2(u1.z); hq[7] = bc_h2(u1.w);                              \
        hq[8] = bc_h2(ut);                                                     \
        float a0 = 0.f, a1 = 0.f, a2 = 0.f, a3 = 0.f, a4 = 0.f;                \
        _Pragma("unroll")                                                      \
        for (int q = 0; q < 9; ++q) {                                          \
            a0 = __builtin_amdgcn_fdot2(hq[q], wq[0][q], a0, false);           \
            a1 = __builtin_amdgcn_fdot2(hq[q], wq[1][q], a1, false);           \
            a2 = __builtin_amdgcn_fdot2(hq[q], wq[2][q], a2, false);           \
            a3 = __builtin_amdgcn_fdot2(hq[q], wq[3][q], a3, false);           \
            a4 = __builtin_amdgcn_fdot2(hq[q], wq[4][q], a4, false);           \
        }                                                                      \
        /* stage-major butterfly: independent ops between dependent pairs */   \
        a0 = dpp_add<0xB1>(a0);  a1 = dpp_add<0xB1>(a1);                       \
        a2 = dpp_add<0xB1>(a2);  a3 = dpp_add<0xB1>(a3);                       \
        a4 = dpp_add<0xB1>(a4);                                                \
        a0 = dpp_add<0x4E>(a0);  a1 = dpp_add<0x4E>(a1);                       \
        a2 = dpp_add<0x4E>(a2);  a3 = dpp_add<0x4E>(a3);                       \
        a4 = dpp_add<0x4E>(a4);                                                \
        a0 = dpp_add<0x141>(a0); a1 = dpp_add<0x141>(a1);                      \
        a2 = dpp_add<0x141>(a2); a3 = dpp_add<0x141>(a3);                      \
        a4 = dpp_add<0x141>(a4);                                               \
        /* tree select (3-deep) instead of 5-deep chain */                     \
        float sl = (ks & 1) ? a1 : a0;                                         \
        float sh = (ks & 1) ? a3 : a2;                                         \
        float s  = (ks & 2) ? sh : sl;                                         \
        s = (ks == 4) ? a4 : s;                                                \
        float z = fmaf((XX), wih0, fmaf((XY), wih1, bias)) + s;                \
        float th = fast_tanh(z);                                               \
        if (wr) (HW)[zrow] = (_Float16)th;                                     \
    }

__global__ __launch_bounds__(THREADS)
void rnn_fused_kernel(const float* __restrict__ x,
                      const float* __restrict__ W_ih,
                      const float* __restrict__ W_hh,
                      const float* __restrict__ b_ih,
                      const float* __restrict__ b_hh,
                      const float* __restrict__ W_fc,
                      const float* __restrict__ b_fc,
                      float* __restrict__ out)
{
    __shared__ __align__(16) _Float16 hA[HPADH];
    __shared__ __align__(16) _Float16 hB[HPADH];

    const int b   = blockIdx.x;
    const int tid = threadIdx.x;
    const int wv  = tid >> 6;       // wave 0..3
    const int g   = tid >> 3;       // global group 0..31 (main rows 4g..4g+3)
    const int ks  = tid & 7;        // k-lane within group

    // extra row: 128 + 2*wv + (g&1)   (128..135; 4 groups redundant each)
    const int erow = 128 + 2 * wv + (g & 1);

    // ---- persistent W_hh f16 pairs: 5 rows x 9 h2 = 45 VGPR ----
    // k map: q<8 -> k = 16*ks + 2q ; q==8 -> k = 128 + 2*ks
    h2 wq[5][9];
#pragma unroll
    for (int j = 0; j < 5; ++j) {
        const int row = (j < 4) ? (4 * g + j) : erow;
#pragma unroll
        for (int q = 0; q < 9; ++q) {
            const int k = (q < 8) ? (16 * ks + 2 * q) : (128 + 2 * ks);
            const float v0 = (k     < HID) ? W_hh[row * HID + k]     : 0.0f;
            const float v1 = (k + 1 < HID) ? W_hh[row * HID + k + 1] : 0.0f;
            wq[j][q] = h2{(_Float16)v0, (_Float16)v1};
        }
    }
    // lane's finished row: ks 0..3 -> main, ks==4 -> extra, 5..7 dummy
    const int zrow = (ks < 4) ? (4 * g + ks) : (ks == 4) ? erow : (4 * g);
    const bool wr  = (ks < 4) || (ks == 4 && ((tid >> 3) & 7) < 2);
    const float wih0 = W_ih[zrow * 2 + 0];
    const float wih1 = W_ih[zrow * 2 + 1];
    const float bias = b_ih[zrow] + b_hh[zrow];

    // ---- zero h buffers (padding stays zero) ----
    if (tid < HPADH) { hA[tid] = (_Float16)0.f; hB[tid] = (_Float16)0.f; }
    __syncthreads();

    // ---- x streamed from global; iteration = 8 steps (one 64 B line);
    //      depth-1 iteration prefetch (~5200 cy of cover) ----
    const float4* xg4 = (const float4*)(x + (size_t)b * (TSTEPS * 2));
    float4 xa = xg4[0], xb = xg4[1], xc = xg4[2], xd = xg4[3];

    for (int t = 0; t < TSTEPS; t += 8) {
        const int tn = ((t + 8) & (TSTEPS - 1)) >> 1;   // float4 index (SALU)
        const float4 ya = xg4[tn + 0];
        const float4 yb = xg4[tn + 1];
        const float4 yc = xg4[tn + 2];
        const float4 yd = xg4[tn + 3];

        RNN_STEP(hA, hB, xa.x, xa.y); __syncthreads();
        RNN_STEP(hB, hA, xa.z, xa.w); __syncthreads();
        RNN_STEP(hA, hB, xb.x, xb.y); __syncthreads();
        RNN_STEP(hB, hA, xb.z, xb.w); __syncthreads();
        RNN_STEP(hA, hB, xc.x, xc.y); __syncthreads();
        RNN_STEP(hB, hA, xc.z, xc.w); __syncthreads();
        RNN_STEP(hA, hB, xd.x, xd.y); __syncthreads();
        RNN_STEP(hB, hA, xd.z, xd.w); __syncthreads();

        xa = ya; xb = yb; xc = yc; xd = yd;
    }
    // TSTEPS % 8 == 0 -> final h in hA

    // ---- final head: out[b][o] = h . W_fc[o,:] + b_fc[o] ----
    if (tid < ODIM) {
        const int o = tid;
        float s = b_fc[o];
#pragma unroll 8
        for (int k = 0; k < HID; ++k)
            s = fmaf((float)hA[k], W_fc[o * HID + k], s);
        out[b * ODIM + o] = s;
    }
}

extern "C" void kernel_launch(void* const* d_in, const int* in_sizes, int n_in,
                              void* d_out, int out_size, void* d_ws, size_t ws_size,
                              hipStream_t stream) {
    const float* x    = (const float*)d_in[0];
    const float* W_ih = (const float*)d_in[1];
    const float* W_hh = (const float*)d_in[2];
    const float* b_ih = (const float*)d_in[3];
    const float* b_hh = (const float*)d_in[4];
    const float* W_fc = (const float*)d_in[5];
    const float* b_fc = (const float*)d_in[6];
    float* out = (float*)d_out;

    rnn_fused_kernel<<<BATCH, THREADS, 0, stream>>>(x, W_ih, W_hh, b_ih, b_hh,
                                                    W_fc, b_fc, out);
}